// Round 3
// baseline (1034.163 us; speedup 1.0000x reference)
//
#include <hip/hip_runtime.h>

#define B_ 2
#define S_ 2048
#define D_ 1024      // D_IN = DKQ = DV = E
#define H_ 16
#define HD_ 64       // DV / H

typedef _Float16 f16;
typedef _Float16 half8 __attribute__((ext_vector_type(8)));
typedef float float4_ __attribute__((ext_vector_type(4)));

#define N_HS (B_*S_*D_)   // 4194304
#define N_W  (D_*D_)      // 1048576
#define N_MIX (H_*D_)     // 16384

__device__ __forceinline__ void gl_lds16(const f16* g, const f16* l) {
  __builtin_amdgcn_global_load_lds(
      (const __attribute__((address_space(1))) void*)g,
      (__attribute__((address_space(3))) void*)l, 16, 0, 0);
}

// raw barrier / counted waits (T3+T4): __syncthreads would drain vmcnt(0)
#define VM_WAIT16() asm volatile("s_waitcnt vmcnt(16)" ::: "memory")
#define VM_WAIT0()  asm volatile("s_waitcnt vmcnt(0)" ::: "memory")
#define LGKM0()     asm volatile("s_waitcnt lgkmcnt(0)" ::: "memory")
#define RAW_BAR()   asm volatile("s_barrier" ::: "memory")
#define SCHED_FENCE() __builtin_amdgcn_sched_barrier(0)

// ---------------- convert fp32 -> fp16 ----------------
// mixing scaled by (1/sqrt(64)) * (1/ln2): softmax exp becomes a bare exp2
#define MIX_SCALE 0.18033688011112042f

__global__ __launch_bounds__(256) void convert_kernel(
    const float* __restrict__ hs, const float* __restrict__ wq,
    const float* __restrict__ wk, const float* __restrict__ wv,
    const float* __restrict__ mix,
    f16* __restrict__ hs16, f16* __restrict__ wq16, f16* __restrict__ wk16,
    f16* __restrict__ wv16, f16* __restrict__ mix16)
{
  const int total4 = (N_HS + 3*N_W + N_MIX) / 4;
  for (int i4 = blockIdx.x*blockDim.x + threadIdx.x; i4 < total4;
       i4 += gridDim.x*blockDim.x) {
    int i = i4*4;
    const float* src; f16* dst; float scale = 1.0f; int off;
    if (i < N_HS)            { src=hs;  dst=hs16;  off=i; }
    else if (i < N_HS+N_W)   { src=wq;  dst=wq16;  off=i-N_HS; }
    else if (i < N_HS+2*N_W) { src=wk;  dst=wk16;  off=i-N_HS-N_W; }
    else if (i < N_HS+3*N_W) { src=wv;  dst=wv16;  off=i-N_HS-2*N_W; }
    else                     { src=mix; dst=mix16; off=i-N_HS-3*N_W; scale=MIX_SCALE; }
    float4 v = *(const float4*)(src+off);
    dst[off]   = (f16)(v.x*scale);
    dst[off+1] = (f16)(v.y*scale);
    dst[off+2] = (f16)(v.z*scale);
    dst[off+3] = (f16)(v.w*scale);
  }
}

// ---------------- QKV GEMM: 128x128 tiles, DMA staging (m97-style) ----------------
// z==2 (V) adds bias and writes TRANSPOSED: vT[b][ch][t]
#define BM 128
#define BN 128
#define BK 64

__global__ __launch_bounds__(256, 2) void qkv_kernel(
    const f16* __restrict__ hs16, const f16* __restrict__ w16base,
    const float* __restrict__ bv,
    f16* __restrict__ q16, f16* __restrict__ k16, f16* __restrict__ vT)
{
  const int z = blockIdx.z;
  const f16* W = w16base + (size_t)z * N_W;
  f16* out = (z==0) ? q16 : k16;
  const int mt = blockIdx.y, nt = blockIdx.x;
  const int tid = threadIdx.x;
  const int lane = tid & 63, wid = tid >> 6;
  const int wm = wid >> 1, wn = wid & 1;
  const int quad = lane >> 4, l16 = lane & 15;

  __shared__ __align__(16) f16 As[BM*BK];   // 16 KB
  __shared__ __align__(16) f16 Bs[BN*BK];   // 16 KB

  float4_ acc[4][4];
#pragma unroll
  for (int i=0;i<4;i++)
#pragma unroll
    for (int j=0;j<4;j++) acc[i][j] = (float4_)0.0f;

  const int row0 = mt*BM;
  const int col0 = nt*BN;

  for (int ko = 0; ko < D_; ko += BK) {
#pragma unroll
    for (int c=0; c<4; c++) {
      int slot = (wid*4+c)*64 + lane;      // 0..1023 16B chunks
      int r = slot >> 3;
      int gc = (slot & 7) ^ (r & 7);
      gl_lds16(hs16 + (size_t)(row0+r)*D_ + ko + gc*8, As + (size_t)(wid*4+c)*64*8);
      gl_lds16(W    + (size_t)(col0+r)*D_ + ko + gc*8, Bs + (size_t)(wid*4+c)*64*8);
    }
    __syncthreads();
#pragma unroll
    for (int kk=0; kk<BK; kk+=32) {
      int ck = (kk >> 3) + quad;
      half8 a[4], b[4];
#pragma unroll
      for (int i=0;i<4;i++) {
        int rr = wm*64 + i*16 + l16;
        a[i] = *(const half8*)&As[(size_t)(((rr<<3) | (ck ^ (rr&7))) << 3)];
      }
#pragma unroll
      for (int j=0;j<4;j++) {
        int rr = wn*64 + j*16 + l16;
        b[j] = *(const half8*)&Bs[(size_t)(((rr<<3) | (ck ^ (rr&7))) << 3)];
      }
#pragma unroll
      for (int i=0;i<4;i++)
#pragma unroll
        for (int j=0;j<4;j++)
          acc[i][j] = __builtin_amdgcn_mfma_f32_16x16x32_f16(a[i], b[j], acc[i][j], 0,0,0);
    }
    __syncthreads();
  }
#pragma unroll
  for (int i=0;i<4;i++) {
#pragma unroll
    for (int j=0;j<4;j++) {
      int colg = col0 + wn*64 + j*16 + l16;
      float bias = (z==2) ? bv[colg] : 0.0f;
#pragma unroll
      for (int r=0;r<4;r++) {
        int rowg = row0 + wm*64 + i*16 + quad*4 + r;
        f16 val = (f16)(acc[i][j][r] + bias);
        if (z == 2) {
          int bb = rowg >> 11, ss = rowg & (S_-1);
          vT[((size_t)bb*D_ + colg)*S_ + ss] = val;
        } else {
          out[(size_t)rowg*D_ + colg] = val;
        }
      }
    }
  }
}

// ---------------- flash attention: counted-vmcnt pipeline ----------------
// Steady state per ko iteration i (16 iters per t0):
//   head: vmcnt(16)  -> waits ONLY pair_i (issued at iter i-2 tail, ~2 iters old)
//         lgkmcnt(0) -> q ds_writes from iter i-1 tail visible
//         s_barrier  (raw: does NOT drain the in-flight pair_{i+1}!)
//   body: 64 MFMA reading k[pair_i] + q_i          (pair_{i+1} DMA in flight)
//         s_barrier  (all reads of pair_i & q_i retired)
//   tail: QWRITE q_{i+1} (regs->LDS), QLOAD q_{i+2}, STAGE pair_{i+2}
// Outstanding-count bookkeeping (per thread, 8 vmem instr per QLOAD/STAGE):
//   at head(i): pair_i(8) + QLOAD_{i+1}(8) + pair_{i+1}(8) = 24 -> vmcnt(16)
//   compiler's own wait at QWRITE consumes QLOAD only (vmcnt(8)), order-safe.
// P is XOR-swizzled [128][128] f16 aliasing exactly k[2..3], so the next-t0
// pair0 prefetch (k[0..1], issued in the PV tt1 phase) rides through P/PV.
// vb(tt0) is issued under iter15's MFMA phase.  XCD swizzle: one batch +
// 4 heads per XCD -> K working set/XCD = 4MB = L2.
#define TQ 128
#define TK 128

__global__ __launch_bounds__(256, 2) void attn_kernel(
    const f16* __restrict__ q16, const f16* __restrict__ k16,
    const f16* __restrict__ vT, const f16* __restrict__ mix16,
    float* __restrict__ out)
{
  // XCD-aware swizzle (bijective: 512 blocks % 8 == 0):
  // hw id = 256b+16h+x; xcd ~ id%8. Remap so each xcd gets one contiguous
  // 64-block chunk: one batch, 4 heads, all 16 s0 tiles (K/XCD = 4MB = L2).
  int id = (blockIdx.z * gridDim.y + blockIdx.y) * gridDim.x + blockIdx.x;
  int swz = (id & 7) * 64 + (id >> 3);
  const int s0 = (swz & 15) * TQ;
  const int h  = (swz >> 4) & 15;
  const int b  = swz >> 8;

  const int tid = threadIdx.x;
  const int lane = tid & 63, wid = tid >> 6;
  const int wm = wid >> 1, wn = wid & 1;
  const int quad = lane >> 4, l16 = lane & 15;

  __shared__ __align__(16) union {
    struct { f16 k[4][TK*BK]; f16 q[TQ*BK]; } s;            // 65536 + 16384 B
    struct { f16 _pad[2*TK*BK]; f16 P[TQ*TK]; } p;          // P = 32KB at k[2..3]
    struct { f16 _pad2[4*TK*BK]; float red_l[2][TQ]; } r;   // red_l aliases q
  } u;

  // swizzled P addressing: chunk (col/8) xor'd with row&7  (16B granules)
#define P_IDX(row, col) ((size_t)((((((row)<<4) | ((((col)>>3) ^ ((row)&7))))<<3)) | ((col)&7)))

  float l_lane[16];
#pragma unroll
  for (int t=0;t<16;t++) l_lane[t] = 0.0f;

  float4_ o_acc[4][2];
#pragma unroll
  for (int i=0;i<4;i++)
#pragma unroll
    for (int j=0;j<2;j++) o_acc[i][j] = (float4_)0.0f;

  const f16* qbase = q16 + (size_t)(b*S_ + s0)*D_;
  const f16* kbase = k16 + (size_t)b*S_*D_;
  const f16* mrow  = mix16 + h*D_;
  const f16* vTb   = vT + (size_t)(b*D_ + h*HD_)*S_;

#define STAGE_PAIR(p, t0g, ko_) do {                                         \
    const f16* k0g_ = kbase + (size_t)(t0g)*D_ + (ko_);                      \
    const f16* k1g_ = k0g_ + (size_t)TK*D_;                                  \
    _Pragma("unroll")                                                        \
    for (int c_=0; c_<4; c_++) {                                             \
      int slot_ = (wid*4+c_)*64 + lane;                                      \
      int r_ = slot_ >> 3;                                                   \
      int gc_ = (slot_ & 7) ^ (r_ & 7);                                      \
      gl_lds16(k0g_ + (size_t)r_*D_ + gc_*8, u.s.k[2*(p)]   + (size_t)(wid*4+c_)*64*8); \
      gl_lds16(k1g_ + (size_t)r_*D_ + gc_*8, u.s.k[2*(p)+1] + (size_t)(wid*4+c_)*64*8); \
    } } while (0)

#define QLOAD(ko_) do {                                                      \
    _Pragma("unroll")                                                        \
    for (int it_=0; it_<4; it_++) {                                          \
      int c_ = it_*256 + tid; int r_ = c_>>3; int cc_ = c_&7;                \
      qv[it_] = *(const half8*)&qbase[(size_t)r_*D_ + (ko_) + cc_*8];        \
      mv[it_] = *(const half8*)&mrow[(ko_) + cc_*8];                         \
    } } while (0)
#define QWRITE() do {                                                        \
    _Pragma("unroll")                                                        \
    for (int it_=0; it_<4; it_++) {                                          \
      int c_ = it_*256 + tid; int r_ = c_>>3; int cc_ = c_&7;                \
      *(half8*)&u.s.q[(size_t)(((r_<<3) | (cc_ ^ (r_&7))) << 3)] = qv[it_]*mv[it_]; \
    } } while (0)

  STAGE_PAIR(0, 0, 0);   // initial pair0 for t0=0
  half8 qv[4], mv[4];

  for (int t0 = 0; t0 < S_; t0 += 2*TK) {
    // ---- t0 prologue (after prev PV-tt1 barrier: q and k[2..3] regions free)
    QLOAD(0);
    QWRITE();               // compiler wait drains QLOAD_0 (+ in-flight pair0; ~1 PV phase old)
    QLOAD(BK);              // q_1 -> regs (OLDER than pair1: keeps pair1 un-drained later)
    STAGE_PAIR(1, t0, BK);  // pair1 -> k[2..3]

    float4_ sacc[2][4][4];
#pragma unroll
    for (int tt=0;tt<2;tt++)
#pragma unroll
      for (int i=0;i<4;i++)
#pragma unroll
        for (int j=0;j<4;j++) sacc[tt][i][j] = (float4_)0.0f;

    half8 vb[8];

#pragma unroll 2
    for (int ko_i = 0; ko_i < D_/BK; ko_i++) {
      const int ko = ko_i * BK;
      const int cur = ko_i & 1;

      if (ko_i == 15) { VM_WAIT0(); } else { VM_WAIT16(); }  // pair_i resident
      LGKM0();                                               // q_i writes visible
      RAW_BAR();
      SCHED_FENCE();

      if (ko_i == 15) {
        // vb(tt0) issued here: hides under the final MFMA phase
#pragma unroll
        for (int ki=0; ki<4; ki++)
#pragma unroll
          for (int j=0; j<2; j++) {
            int ch = wn*32 + j*16 + l16;
            vb[ki*2+j] = *(const half8*)&vTb[(size_t)ch*S_ + t0 + ki*32 + quad*8];
          }
      }

      __builtin_amdgcn_s_setprio(1);
#pragma unroll
      for (int kk2=0; kk2<2; kk2++) {
        half8 a[4];
#pragma unroll
        for (int i=0;i<4;i++) {
          int rr = wm*64 + i*16 + l16;
          int ck = kk2*4 + quad;
          a[i] = *(const half8*)&u.s.q[(size_t)(((rr<<3) | (ck ^ (rr&7))) << 3)];
        }
#pragma unroll
        for (int tt=0;tt<2;tt++) {
          const f16* kb = u.s.k[2*cur + tt];
          half8 bf[4];
#pragma unroll
          for (int j=0;j<4;j++) {
            int rr = wn*64 + j*16 + l16;
            int ck = kk2*4 + quad;
            bf[j] = *(const half8*)&kb[(size_t)(((rr<<3) | (ck ^ (rr&7))) << 3)];
          }
#pragma unroll
          for (int i=0;i<4;i++)
#pragma unroll
            for (int j=0;j<4;j++)
              sacc[tt][i][j] = __builtin_amdgcn_mfma_f32_16x16x32_f16(a[i], bf[j], sacc[tt][i][j], 0,0,0);
        }
      }
      __builtin_amdgcn_s_setprio(0);

      RAW_BAR();            // all reads of pair_i & q_i retired
      SCHED_FENCE();

      if (ko_i < 14) {
        QWRITE();                         // q_{i+1} -> LDS (compiler: vmcnt(8))
        QLOAD(ko + 2*BK);                 // q_{i+2} -> regs
        STAGE_PAIR(cur, t0, ko + 2*BK);   // pair_{i+2} -> freed buffer of pair_i
      } else if (ko_i == 14) {
        QWRITE();                         // q_15
      }
    }
    // after iter15's trailing barrier: all k/q reads done; outstanding vmem = vb(8)

    // ---- PV tt = 0 : P=exp2(S), l partials, P->LDS (k[2..3] region), PV ----
#pragma unroll
    for (int i=0;i<4;i++)
#pragma unroll
      for (int j=0;j<4;j++)
#pragma unroll
        for (int r=0;r<4;r++) {
          float p = __builtin_exp2f(sacc[0][i][j][r]);
          l_lane[i*4+r] += p;
          u.p.P[P_IDX(wm*64+i*16+quad*4+r, wn*64+j*16+l16)] = (f16)p;
        }
    LGKM0();
    RAW_BAR();
    SCHED_FENCE();

    __builtin_amdgcn_s_setprio(1);
#pragma unroll
    for (int ki=0; ki<4; ki++) {
      half8 pa[4];
#pragma unroll
      for (int i=0;i<4;i++)
        pa[i] = *(const half8*)&u.p.P[P_IDX(wm*64+i*16+l16, ki*32+quad*8)];
#pragma unroll
      for (int i=0;i<4;i++)
#pragma unroll
        for (int j=0;j<2;j++)
          o_acc[i][j] = __builtin_amdgcn_mfma_f32_16x16x32_f16(pa[i], vb[ki*2+j], o_acc[i][j], 0,0,0);
    }
    __builtin_amdgcn_s_setprio(0);
    RAW_BAR();              // PV tt0 P-reads retired -> tt1 may overwrite P
    SCHED_FENCE();

    // ---- PV tt = 1 ----
#pragma unroll
    for (int i=0;i<4;i++)
#pragma unroll
      for (int j=0;j<4;j++)
#pragma unroll
        for (int r=0;r<4;r++) {
          float p = __builtin_exp2f(sacc[1][i][j][r]);
          l_lane[i*4+r] += p;
          u.p.P[P_IDX(wm*64+i*16+quad*4+r, wn*64+j*16+l16)] = (f16)p;
        }
    // vb(tt1) FIRST, then next-t0 pair0 DMA (k[0..1], free since iter14):
    // compiler's wait for vb -> vmcnt(8), leaving the DMA in flight.
#pragma unroll
    for (int ki=0; ki<4; ki++)
#pragma unroll
      for (int j=0; j<2; j++) {
        int ch = wn*32 + j*16 + l16;
        vb[ki*2+j] = *(const half8*)&vTb[(size_t)ch*S_ + t0 + TK + ki*32 + quad*8];
      }
    if (t0 + 2*TK < S_) STAGE_PAIR(0, t0 + 2*TK, 0);
    LGKM0();
    RAW_BAR();
    SCHED_FENCE();

    __builtin_amdgcn_s_setprio(1);
#pragma unroll
    for (int ki=0; ki<4; ki++) {
      half8 pa[4];
#pragma unroll
      for (int i=0;i<4;i++)
        pa[i] = *(const half8*)&u.p.P[P_IDX(wm*64+i*16+l16, ki*32+quad*8)];
#pragma unroll
      for (int i=0;i<4;i++)
#pragma unroll
        for (int j=0;j<2;j++)
          o_acc[i][j] = __builtin_amdgcn_mfma_f32_16x16x32_f16(pa[i], vb[ki*2+j], o_acc[i][j], 0,0,0);
    }
    __builtin_amdgcn_s_setprio(0);
    RAW_BAR();              // P reads retired -> next t0 may stage into k[2..3]
    SCHED_FENCE();
  }

  // ---- epilogue: single l reduction (butterfly over l16, cross-wave via LDS) ----
#pragma unroll
  for (int d=1; d<16; d<<=1)
#pragma unroll
    for (int t=0;t<16;t++) l_lane[t] += __shfl_xor(l_lane[t], d);
  if (l16 == 0) {
#pragma unroll
    for (int i=0;i<4;i++)
#pragma unroll
      for (int r=0;r<4;r++)
        u.r.red_l[wn][wm*64+i*16+quad*4+r] = l_lane[i*4+r];
  }
  __syncthreads();

#pragma unroll
  for (int i=0;i<4;i++) {
#pragma unroll
    for (int r=0;r<4;r++) {
      int row = wm*64 + i*16 + quad*4 + r;
      float linv = 1.0f / (u.r.red_l[0][row] + u.r.red_l[1][row]);
#pragma unroll
      for (int j=0;j<2;j++) {
        int colg = h*HD_ + wn*32 + j*16 + l16;
        out[(size_t)(b*S_ + s0 + row)*D_ + colg] = o_acc[i][j][r] * linv;
      }
    }
  }
}

// ---------------- launch ----------------
extern "C" void kernel_launch(void* const* d_in, const int* in_sizes, int n_in,
                              void* d_out, int out_size, void* d_ws, size_t ws_size,
                              hipStream_t stream) {
  (void)in_sizes; (void)n_in; (void)out_size; (void)ws_size;
  const float* hs  = (const float*)d_in[0];
  const float* Wq  = (const float*)d_in[1];
  const float* Wk  = (const float*)d_in[2];
  const float* Wv  = (const float*)d_in[3];
  const float* bv  = (const float*)d_in[4];
  const float* mix = (const float*)d_in[5];
  float* out = (float*)d_out;

  char* ws = (char*)d_ws;
  f16* hs16  = (f16*)(ws);                       // 8 MB
  f16* w16   = (f16*)(ws + 8388608);             // 6 MB
  f16* mix16 = (f16*)(ws + 14680064);            // 32 KB
  f16* q16   = (f16*)(ws + 14712832);            // 8 MB
  f16* k16   = (f16*)(ws + 23101440);            // 8 MB
  f16* vT    = (f16*)(ws + 31490048);            // 8 MB

  convert_kernel<<<2048, 256, 0, stream>>>(hs, Wq, Wk, Wv, mix,
                                           hs16, w16, w16+N_W, w16+2*N_W, mix16);
  qkv_kernel<<<dim3(D_/BN, (B_*S_)/BM, 3), 256, 0, stream>>>(
      hs16, w16, bv, q16, k16, vT);
  attn_kernel<<<dim3(S_/TQ, H_, B_), 256, 0, stream>>>(
      q16, k16, vT, mix16, out);
}

// Round 4
// 970.715 us; speedup vs baseline: 1.0654x; 1.0654x over previous
//
#include <hip/hip_runtime.h>

#define B_ 2
#define S_ 2048
#define D_ 1024      // D_IN = DKQ = DV = E
#define H_ 16
#define HD_ 64       // DV / H

typedef _Float16 f16;
typedef _Float16 half8 __attribute__((ext_vector_type(8)));
typedef float float4_ __attribute__((ext_vector_type(4)));

#define N_HS (B_*S_*D_)   // 4194304
#define N_W  (D_*D_)      // 1048576
#define N_MIX (H_*D_)     // 16384

__device__ __forceinline__ void gl_lds16(const f16* g, const f16* l) {
  __builtin_amdgcn_global_load_lds(
      (const __attribute__((address_space(1))) void*)g,
      (__attribute__((address_space(3))) void*)l, 16, 0, 0);
}

// counted waits + raw barrier (T3+T4). __syncthreads would drain vmcnt(0).
#define VM_WAIT8()  asm volatile("s_waitcnt vmcnt(8)" ::: "memory")
#define LGKM0()     asm volatile("s_waitcnt lgkmcnt(0)" ::: "memory")
#define RAW_BAR()   asm volatile("s_barrier" ::: "memory")
#define SCHED_FENCE() __builtin_amdgcn_sched_barrier(0)

// ---------------- convert fp32 -> fp16 ----------------
// mixing scaled by (1/sqrt(64)) * (1/ln2): softmax exp becomes a bare exp2
#define MIX_SCALE 0.18033688011112042f

__global__ __launch_bounds__(256) void convert_kernel(
    const float* __restrict__ hs, const float* __restrict__ wq,
    const float* __restrict__ wk, const float* __restrict__ wv,
    const float* __restrict__ mix,
    f16* __restrict__ hs16, f16* __restrict__ wq16, f16* __restrict__ wk16,
    f16* __restrict__ wv16, f16* __restrict__ mix16)
{
  const int total4 = (N_HS + 3*N_W + N_MIX) / 4;
  for (int i4 = blockIdx.x*blockDim.x + threadIdx.x; i4 < total4;
       i4 += gridDim.x*blockDim.x) {
    int i = i4*4;
    const float* src; f16* dst; float scale = 1.0f; int off;
    if (i < N_HS)            { src=hs;  dst=hs16;  off=i; }
    else if (i < N_HS+N_W)   { src=wq;  dst=wq16;  off=i-N_HS; }
    else if (i < N_HS+2*N_W) { src=wk;  dst=wk16;  off=i-N_HS-N_W; }
    else if (i < N_HS+3*N_W) { src=wv;  dst=wv16;  off=i-N_HS-2*N_W; }
    else                     { src=mix; dst=mix16; off=i-N_HS-3*N_W; scale=MIX_SCALE; }
    float4 v = *(const float4*)(src+off);
    dst[off]   = (f16)(v.x*scale);
    dst[off+1] = (f16)(v.y*scale);
    dst[off+2] = (f16)(v.z*scale);
    dst[off+3] = (f16)(v.w*scale);
  }
}

// ---------------- QKV GEMM: 128x128 tiles, DMA staging (m97-style) ----------------
// z==2 (V) adds bias and writes TRANSPOSED: vT[b][ch][t]
#define BM 128
#define BN 128
#define BK 64

__global__ __launch_bounds__(256, 2) void qkv_kernel(
    const f16* __restrict__ hs16, const f16* __restrict__ w16base,
    const float* __restrict__ bv,
    f16* __restrict__ q16, f16* __restrict__ k16, f16* __restrict__ vT)
{
  const int z = blockIdx.z;
  const f16* W = w16base + (size_t)z * N_W;
  f16* out = (z==0) ? q16 : k16;
  const int mt = blockIdx.y, nt = blockIdx.x;
  const int tid = threadIdx.x;
  const int lane = tid & 63, wid = tid >> 6;
  const int wm = wid >> 1, wn = wid & 1;
  const int quad = lane >> 4, l16 = lane & 15;

  __shared__ __align__(16) f16 As[BM*BK];   // 16 KB
  __shared__ __align__(16) f16 Bs[BN*BK];   // 16 KB

  float4_ acc[4][4];
#pragma unroll
  for (int i=0;i<4;i++)
#pragma unroll
    for (int j=0;j<4;j++) acc[i][j] = (float4_)0.0f;

  const int row0 = mt*BM;
  const int col0 = nt*BN;

  for (int ko = 0; ko < D_; ko += BK) {
#pragma unroll
    for (int c=0; c<4; c++) {
      int slot = (wid*4+c)*64 + lane;      // 0..1023 16B chunks
      int r = slot >> 3;
      int gc = (slot & 7) ^ (r & 7);
      gl_lds16(hs16 + (size_t)(row0+r)*D_ + ko + gc*8, As + (size_t)(wid*4+c)*64*8);
      gl_lds16(W    + (size_t)(col0+r)*D_ + ko + gc*8, Bs + (size_t)(wid*4+c)*64*8);
    }
    __syncthreads();
#pragma unroll
    for (int kk=0; kk<BK; kk+=32) {
      int ck = (kk >> 3) + quad;
      half8 a[4], b[4];
#pragma unroll
      for (int i=0;i<4;i++) {
        int rr = wm*64 + i*16 + l16;
        a[i] = *(const half8*)&As[(size_t)(((rr<<3) | (ck ^ (rr&7))) << 3)];
      }
#pragma unroll
      for (int j=0;j<4;j++) {
        int rr = wn*64 + j*16 + l16;
        b[j] = *(const half8*)&Bs[(size_t)(((rr<<3) | (ck ^ (rr&7))) << 3)];
      }
#pragma unroll
      for (int i=0;i<4;i++)
#pragma unroll
        for (int j=0;j<4;j++)
          acc[i][j] = __builtin_amdgcn_mfma_f32_16x16x32_f16(a[i], b[j], acc[i][j], 0,0,0);
    }
    __syncthreads();
  }
#pragma unroll
  for (int i=0;i<4;i++) {
#pragma unroll
    for (int j=0;j<4;j++) {
      int colg = col0 + wn*64 + j*16 + l16;
      float bias = (z==2) ? bv[colg] : 0.0f;
#pragma unroll
      for (int r=0;r<4;r++) {
        int rowg = row0 + wm*64 + i*16 + quad*4 + r;
        f16 val = (f16)(acc[i][j][r] + bias);
        if (z == 2) {
          int bb = rowg >> 11, ss = rowg & (S_-1);
          vT[((size_t)bb*D_ + colg)*S_ + ss] = val;
        } else {
          out[(size_t)rowg*D_ + colg] = val;
        }
      }
    }
  }
}

// ---------------- flash attention: counted-vmcnt, R0 register structure ----------------
// Per ko (16 iters per t0), slot(i) = i&1 holds pair_i (k-tiles t0 / t0+128 at
// k-slice i):
//   head: [i<15: vmcnt(8)]  -> pair_i resident, pair_{i+1} stays in flight
//         lgkmcnt(0); s_barrier            (raw: no vmcnt(0) drain)
//   body: 64 MFMA on q_i (LDS) x pair_i    (pair_{i+1} DMA in flight)
//   tail: lgkmcnt(0); s_barrier            (reads of pair_i, q_i retired)
//         [qv loads | fence | STAGE pair_{i+2} -> slot(i) | fence | QWRITE]
//         QWRITE's compiler wait = vmcnt(8): drains qv only, pair stays.
//         (i==14 stages next-t0 pair0; i==15 stages next-t0 q_0 + vb_tt0)
// NO register state lives across the MFMA cluster (R0 discipline: the R1-R3
// WRITE_SIZE explosion (300-700MB vs 16MB output) was scratch spill from
// live-across qv/mv).  P = unpadded XOR-swizzled 32KB at k-slots 2..3, so
// slots 0..1 are free during PV for next-t0 staging.  No XCD swizzle (R3:
// FETCH tripled with it; R0's 70MB was already fine).
#define TQ 128
#define TK 128

__global__ __launch_bounds__(256, 2) void attn_kernel(
    const f16* __restrict__ q16, const f16* __restrict__ k16,
    const f16* __restrict__ vT, const f16* __restrict__ mix16,
    float* __restrict__ out)
{
  const int b = blockIdx.z;
  const int h = blockIdx.y;
  const int s0 = blockIdx.x * TQ;
  const int tid = threadIdx.x;
  const int lane = tid & 63, wid = tid >> 6;
  const int wm = wid >> 1, wn = wid & 1;
  const int quad = lane >> 4, l16 = lane & 15;

  __shared__ __align__(16) union {
    struct { f16 k[4][TK*BK]; f16 q[TQ*BK]; } s;     // 64KB + 16KB = 81920 B
    struct { f16 _pad[2*TK*BK]; f16 P[TQ*TK]; } p;   // P = 32KB at slots 2..3
    struct { float red_l[2][TQ]; } r;                // epilogue only
  } u;

  // P swizzle: 16B chunk index (col>>3) xor'd with row&7; bijective per row
#define P_IDX(row, col) ((size_t)((((row)<<7)) | (((((col)>>3) ^ ((row)&7)))<<3) | ((col)&7)))

  float l_lane[16];
#pragma unroll
  for (int t=0;t<16;t++) l_lane[t] = 0.0f;

  float4_ o_acc[4][2];
#pragma unroll
  for (int i=0;i<4;i++)
#pragma unroll
    for (int j=0;j<2;j++) o_acc[i][j] = (float4_)0.0f;

  const f16* qbase = q16 + (size_t)(b*S_ + s0)*D_;
  const f16* kbase = k16 + (size_t)b*S_*D_;
  const f16* mrow  = mix16 + h*D_;
  const f16* vTb   = vT + (size_t)(b*D_ + h*HD_)*S_;

#define STAGE_PAIR(p, t0g, ko_) do {                                         \
    const f16* k0g_ = kbase + (size_t)(t0g)*D_ + (ko_);                      \
    const f16* k1g_ = k0g_ + (size_t)TK*D_;                                  \
    _Pragma("unroll")                                                        \
    for (int c_=0; c_<4; c_++) {                                             \
      int slot_ = (wid*4+c_)*64 + lane;                                      \
      int r_ = slot_ >> 3;                                                   \
      int gc_ = (slot_ & 7) ^ (r_ & 7);                                      \
      gl_lds16(k0g_ + (size_t)r_*D_ + gc_*8, u.s.k[2*(p)]   + (size_t)(wid*4+c_)*64*8); \
      gl_lds16(k1g_ + (size_t)r_*D_ + gc_*8, u.s.k[2*(p)+1] + (size_t)(wid*4+c_)*64*8); \
    } } while (0)

  // q staging: transient regs only (load -> fence -> (stage) -> fence -> mul+write)
#define QLOAD(ko_) do {                                                      \
    _Pragma("unroll")                                                        \
    for (int it_=0; it_<4; it_++) {                                          \
      int c_ = it_*256 + tid; int r_ = c_>>3; int cc_ = c_&7;                \
      qv[it_] = *(const half8*)&qbase[(size_t)r_*D_ + (ko_) + cc_*8];        \
      mv[it_] = *(const half8*)&mrow[(ko_) + cc_*8];                         \
    } } while (0)
#define QWRITE() do {                                                        \
    _Pragma("unroll")                                                        \
    for (int it_=0; it_<4; it_++) {                                          \
      int c_ = it_*256 + tid; int r_ = c_>>3; int cc_ = c_&7;                \
      *(half8*)&u.s.q[(size_t)(((r_<<3) | (cc_ ^ (r_&7))) << 3)] = qv[it_]*mv[it_]; \
    } } while (0)

  half8 qv[4], mv[4];
  half8 vb[8];

  // kernel prologue: pairs 0,1 + q_0 (the one vmcnt(0)-ish drain, once)
  STAGE_PAIR(0, 0, 0);
  STAGE_PAIR(1, 0, BK);
  QLOAD(0);
  QWRITE();

  for (int t0 = 0; t0 < S_; t0 += 2*TK) {
    const bool has_next = (t0 + 2*TK < S_);

    float4_ sacc[2][4][4];
#pragma unroll
    for (int tt=0;tt<2;tt++)
#pragma unroll
      for (int i=0;i<4;i++)
#pragma unroll
        for (int j=0;j<4;j++) sacc[tt][i][j] = (float4_)0.0f;

#pragma unroll 2
    for (int ko_i = 0; ko_i < D_/BK; ko_i++) {
      const int ko = ko_i * BK;
      const int cur = ko_i & 1;

      // ---- head ----
      if (ko_i < 15) VM_WAIT8();   // pair_i resident; i==15 forced by tail(14)'s qv wait
      LGKM0();
      RAW_BAR();
      SCHED_FENCE();

      // ---- MFMA phase (pair_{i+1} DMA in flight) ----
      __builtin_amdgcn_s_setprio(1);
#pragma unroll
      for (int kk2=0; kk2<2; kk2++) {
        half8 a[4];
#pragma unroll
        for (int i=0;i<4;i++) {
          int rr = wm*64 + i*16 + l16;
          int ck = kk2*4 + quad;
          a[i] = *(const half8*)&u.s.q[(size_t)(((rr<<3) | (ck ^ (rr&7))) << 3)];
        }
#pragma unroll
        for (int tt=0;tt<2;tt++) {
          const f16* kb = u.s.k[2*cur + tt];
          half8 bf[4];
#pragma unroll
          for (int j=0;j<4;j++) {
            int rr = wn*64 + j*16 + l16;
            int ck = kk2*4 + quad;
            bf[j] = *(const half8*)&kb[(size_t)(((rr<<3) | (ck ^ (rr&7))) << 3)];
          }
#pragma unroll
          for (int i=0;i<4;i++)
#pragma unroll
            for (int j=0;j<4;j++)
              sacc[tt][i][j] = __builtin_amdgcn_mfma_f32_16x16x32_f16(a[i], bf[j], sacc[tt][i][j], 0,0,0);
        }
      }
      __builtin_amdgcn_s_setprio(0);

      // ---- tail ----
      LGKM0();
      RAW_BAR();
      SCHED_FENCE();

      if (ko_i < 15) {
        QLOAD(ko + BK);                          // q_{i+1} (oldest in this region)
        SCHED_FENCE();
        if (ko_i < 14)       STAGE_PAIR(cur, t0, ko + 2*BK);       // pair_{i+2}
        else if (has_next)   STAGE_PAIR(0, t0 + 2*TK, 0);          // next-t0 pair0 (slot0 = cur)
        SCHED_FENCE();
        QWRITE();                                // compiler wait: vmcnt(8) -> pair rides
      } else {
        if (has_next) QLOAD(0);                  // next-t0 q_0 (same q rows, slice 0)
        SCHED_FENCE();
#pragma unroll
        for (int ki=0; ki<4; ki++)               // vb for PV tt0
#pragma unroll
          for (int j=0; j<2; j++) {
            int ch = wn*32 + j*16 + l16;
            vb[ki*2+j] = *(const half8*)&vTb[(size_t)ch*S_ + t0 + ki*32 + quad*8];
          }
        SCHED_FENCE();
        if (has_next) QWRITE();                  // vmcnt(8): drains qv, vb stays
      }
    }

    // ---- PV tt = 0 : P writes (slots 2..3; k/q reads all retired) ----
#pragma unroll
    for (int i=0;i<4;i++)
#pragma unroll
      for (int j=0;j<4;j++)
#pragma unroll
        for (int r=0;r<4;r++) {
          float ptmp = __builtin_exp2f(sacc[0][i][j][r]);
          l_lane[i*4+r] += ptmp;
          u.p.P[P_IDX(wm*64+i*16+quad*4+r, wn*64+j*16+l16)] = (f16)ptmp;
        }
    LGKM0();
    RAW_BAR();
    SCHED_FENCE();

    __builtin_amdgcn_s_setprio(1);
#pragma unroll
    for (int ki=0; ki<4; ki++) {
      half8 pa[4];
#pragma unroll
      for (int i=0;i<4;i++)
        pa[i] = *(const half8*)&u.p.P[P_IDX(wm*64+i*16+l16, ki*32+quad*8)];
#pragma unroll
      for (int i=0;i<4;i++)
#pragma unroll
        for (int j=0;j<2;j++)
          o_acc[i][j] = __builtin_amdgcn_mfma_f32_16x16x32_f16(pa[i], vb[ki*2+j], o_acc[i][j], 0,0,0);
    }
    __builtin_amdgcn_s_setprio(0);
    LGKM0();
    RAW_BAR();       // P(tt0) reads retired -> tt1 may overwrite
    SCHED_FENCE();

    // ---- PV tt = 1 ----
#pragma unroll
    for (int i=0;i<4;i++)
#pragma unroll
      for (int j=0;j<4;j++)
#pragma unroll
        for (int r=0;r<4;r++) {
          float ptmp = __builtin_exp2f(sacc[1][i][j][r]);
          l_lane[i*4+r] += ptmp;
          u.p.P[P_IDX(wm*64+i*16+quad*4+r, wn*64+j*16+l16)] = (f16)ptmp;
        }
#pragma unroll
    for (int ki=0; ki<4; ki++)                   // vb for PV tt1
#pragma unroll
      for (int j=0; j<2; j++) {
        int ch = wn*32 + j*16 + l16;
        vb[ki*2+j] = *(const half8*)&vTb[(size_t)ch*S_ + t0 + TK + ki*32 + quad*8];
      }
    LGKM0();
    RAW_BAR();
    SCHED_FENCE();

    __builtin_amdgcn_s_setprio(1);
#pragma unroll
    for (int ki=0; ki<4; ki++) {
      half8 pa[4];
#pragma unroll
      for (int i=0;i<4;i++)
        pa[i] = *(const half8*)&u.p.P[P_IDX(wm*64+i*16+l16, ki*32+quad*8)];
#pragma unroll
      for (int i=0;i<4;i++)
#pragma unroll
        for (int j=0;j<2;j++)
          o_acc[i][j] = __builtin_amdgcn_mfma_f32_16x16x32_f16(pa[i], vb[ki*2+j], o_acc[i][j], 0,0,0);
    }
    __builtin_amdgcn_s_setprio(0);
    LGKM0();
    RAW_BAR();       // P(tt1) reads retired -> slot1 free for next-t0 pair1
    SCHED_FENCE();

    if (has_next) STAGE_PAIR(1, t0 + 2*TK, BK);  // lands under head(0..1) of next t0
  }

  // ---- epilogue: single l reduction (butterfly over l16, cross-wave via LDS) ----
#pragma unroll
  for (int d=1; d<16; d<<=1)
#pragma unroll
    for (int t=0;t<16;t++) l_lane[t] += __shfl_xor(l_lane[t], d);
  if (l16 == 0) {
#pragma unroll
    for (int i=0;i<4;i++)
#pragma unroll
      for (int r=0;r<4;r++)
        u.r.red_l[wn][wm*64+i*16+quad*4+r] = l_lane[i*4+r];
  }
  __syncthreads();

#pragma unroll
  for (int i=0;i<4;i++) {
#pragma unroll
    for (int r=0;r<4;r++) {
      int row = wm*64 + i*16 + quad*4 + r;
      float linv = 1.0f / (u.r.red_l[0][row] + u.r.red_l[1][row]);
#pragma unroll
      for (int j=0;j<2;j++) {
        int colg = h*HD_ + wn*32 + j*16 + l16;
        out[(size_t)(b*S_ + s0 + row)*D_ + colg] = o_acc[i][j][r] * linv;
      }
    }
  }
}

// ---------------- launch ----------------
extern "C" void kernel_launch(void* const* d_in, const int* in_sizes, int n_in,
                              void* d_out, int out_size, void* d_ws, size_t ws_size,
                              hipStream_t stream) {
  (void)in_sizes; (void)n_in; (void)out_size; (void)ws_size;
  const float* hs  = (const float*)d_in[0];
  const float* Wq  = (const float*)d_in[1];
  const float* Wk  = (const float*)d_in[2];
  const float* Wv  = (const float*)d_in[3];
  const float* bv  = (const float*)d_in[4];
  const float* mix = (const float*)d_in[5];
  float* out = (float*)d_out;

  char* ws = (char*)d_ws;
  f16* hs16  = (f16*)(ws);                       // 8 MB
  f16* w16   = (f16*)(ws + 8388608);             // 6 MB
  f16* mix16 = (f16*)(ws + 14680064);            // 32 KB
  f16* q16   = (f16*)(ws + 14712832);            // 8 MB
  f16* k16   = (f16*)(ws + 23101440);            // 8 MB
  f16* vT    = (f16*)(ws + 31490048);            // 8 MB

  convert_kernel<<<2048, 256, 0, stream>>>(hs, Wq, Wk, Wv, mix,
                                           hs16, w16, w16+N_W, w16+2*N_W, mix16);
  qkv_kernel<<<dim3(D_/BN, (B_*S_)/BM, 3), 256, 0, stream>>>(
      hs16, w16, bv, q16, k16, vT);
  attn_kernel<<<dim3(S_/TQ, H_, B_), 256, 0, stream>>>(
      q16, k16, vT, mix16, out);
}

// Round 5
// 646.432 us; speedup vs baseline: 1.5998x; 1.5017x over previous
//
#include <hip/hip_runtime.h>

#define B_ 2
#define S_ 2048
#define D_ 1024      // D_IN = DKQ = DV = E
#define H_ 16
#define HD_ 64       // DV / H

typedef _Float16 f16;
typedef _Float16 half8 __attribute__((ext_vector_type(8)));
typedef float float4_ __attribute__((ext_vector_type(4)));

#define N_HS (B_*S_*D_)   // 4194304
#define N_W  (D_*D_)      // 1048576
#define N_MIX (H_*D_)     // 16384

__device__ __forceinline__ void gl_lds16(const f16* g, const f16* l) {
  __builtin_amdgcn_global_load_lds(
      (const __attribute__((address_space(1))) void*)g,
      (__attribute__((address_space(3))) void*)l, 16, 0, 0);
}

// ---------------- convert fp32 -> fp16 ----------------
// mixing scaled by (1/sqrt(64)) * (1/ln2): softmax exp becomes a bare exp2
#define MIX_SCALE 0.18033688011112042f

__global__ __launch_bounds__(256) void convert_kernel(
    const float* __restrict__ hs, const float* __restrict__ wq,
    const float* __restrict__ wk, const float* __restrict__ wv,
    const float* __restrict__ mix,
    f16* __restrict__ hs16, f16* __restrict__ wq16, f16* __restrict__ wk16,
    f16* __restrict__ wv16, f16* __restrict__ mix16)
{
  const int total4 = (N_HS + 3*N_W + N_MIX) / 4;
  for (int i4 = blockIdx.x*blockDim.x + threadIdx.x; i4 < total4;
       i4 += gridDim.x*blockDim.x) {
    int i = i4*4;
    const float* src; f16* dst; float scale = 1.0f; int off;
    if (i < N_HS)            { src=hs;  dst=hs16;  off=i; }
    else if (i < N_HS+N_W)   { src=wq;  dst=wq16;  off=i-N_HS; }
    else if (i < N_HS+2*N_W) { src=wk;  dst=wk16;  off=i-N_HS-N_W; }
    else if (i < N_HS+3*N_W) { src=wv;  dst=wv16;  off=i-N_HS-2*N_W; }
    else                     { src=mix; dst=mix16; off=i-N_HS-3*N_W; scale=MIX_SCALE; }
    float4 v = *(const float4*)(src+off);
    dst[off]   = (f16)(v.x*scale);
    dst[off+1] = (f16)(v.y*scale);
    dst[off+2] = (f16)(v.z*scale);
    dst[off+3] = (f16)(v.w*scale);
  }
}

// ---------------- QKV GEMM: 128x128 tiles, DMA staging (m97-style) ----------------
// z==2 (V) adds bias and writes TRANSPOSED: vT[b][ch][t]
#define BM 128
#define BN 128
#define BK 64

__global__ __launch_bounds__(256, 2) void qkv_kernel(
    const f16* __restrict__ hs16, const f16* __restrict__ w16base,
    const float* __restrict__ bv,
    f16* __restrict__ q16, f16* __restrict__ k16, f16* __restrict__ vT)
{
  const int z = blockIdx.z;
  const f16* W = w16base + (size_t)z * N_W;
  f16* out = (z==0) ? q16 : k16;
  const int mt = blockIdx.y, nt = blockIdx.x;
  const int tid = threadIdx.x;
  const int lane = tid & 63, wid = tid >> 6;
  const int wm = wid >> 1, wn = wid & 1;
  const int quad = lane >> 4, l16 = lane & 15;

  __shared__ __align__(16) f16 As[BM*BK];   // 16 KB
  __shared__ __align__(16) f16 Bs[BN*BK];   // 16 KB

  float4_ acc[4][4];
#pragma unroll
  for (int i=0;i<4;i++)
#pragma unroll
    for (int j=0;j<4;j++) acc[i][j] = (float4_)0.0f;

  const int row0 = mt*BM;
  const int col0 = nt*BN;

  for (int ko = 0; ko < D_; ko += BK) {
#pragma unroll
    for (int c=0; c<4; c++) {
      int slot = (wid*4+c)*64 + lane;      // 0..1023 16B chunks
      int r = slot >> 3;
      int gc = (slot & 7) ^ (r & 7);
      gl_lds16(hs16 + (size_t)(row0+r)*D_ + ko + gc*8, As + (size_t)(wid*4+c)*64*8);
      gl_lds16(W    + (size_t)(col0+r)*D_ + ko + gc*8, Bs + (size_t)(wid*4+c)*64*8);
    }
    __syncthreads();
#pragma unroll
    for (int kk=0; kk<BK; kk+=32) {
      int ck = (kk >> 3) + quad;
      half8 a[4], b[4];
#pragma unroll
      for (int i=0;i<4;i++) {
        int rr = wm*64 + i*16 + l16;
        a[i] = *(const half8*)&As[(size_t)(((rr<<3) | (ck ^ (rr&7))) << 3)];
      }
#pragma unroll
      for (int j=0;j<4;j++) {
        int rr = wn*64 + j*16 + l16;
        b[j] = *(const half8*)&Bs[(size_t)(((rr<<3) | (ck ^ (rr&7))) << 3)];
      }
#pragma unroll
      for (int i=0;i<4;i++)
#pragma unroll
        for (int j=0;j<4;j++)
          acc[i][j] = __builtin_amdgcn_mfma_f32_16x16x32_f16(a[i], b[j], acc[i][j], 0,0,0);
    }
    __syncthreads();
  }
#pragma unroll
  for (int i=0;i<4;i++) {
#pragma unroll
    for (int j=0;j<4;j++) {
      int colg = col0 + wn*64 + j*16 + l16;
      float bias = (z==2) ? bv[colg] : 0.0f;
#pragma unroll
      for (int r=0;r<4;r++) {
        int rowg = row0 + wm*64 + i*16 + quad*4 + r;
        f16 val = (f16)(acc[i][j][r] + bias);
        if (z == 2) {
          int bb = rowg >> 11, ss = rowg & (S_-1);
          vT[((size_t)bb*D_ + colg)*S_ + ss] = val;
        } else {
          out[(size_t)rowg*D_ + colg] = val;
        }
      }
    }
  }
}

// ---------------- flash attention: small-tile, all-DMA, 3 blocks/CU ----------------
// Design (post R1-R4 failures): register-held prefetch state caused scratch
// spills (WRITE_SIZE 300-750MB vs 16MB output).  Fixes:
//  * ALL staging is global_load_lds DMA (zero registers in flight):
//    raw q staged via DMA; mixing applied on the A-FRAGMENT after ds_read
//    (1 broadcast half8 load of mrow + 4 pk_mul per kk2).
//  * single k-tile per pass: sacc[4][4]=64 regs (was 128).  Peak live ~158.
//  * LDS 33.8KB (k 16K + q 16K, P 32K aliases both) + launch_bounds(256,3)
//    -> 3 blocks/CU: each __syncthreads vmcnt-drain is hidden by TWO other
//    blocks' MFMA phases (the 2-block R0 config could only half-hide it).
//  * plain __syncthreads only; no raw barriers / counted vmcnt / sched fences.
#define TQ 128
#define TK 128

__global__ __launch_bounds__(256, 3) void attn_kernel(
    const f16* __restrict__ q16, const f16* __restrict__ k16,
    const f16* __restrict__ vT, const f16* __restrict__ mix16,
    float* __restrict__ out)
{
  const int b = blockIdx.z;
  const int h = blockIdx.y;
  const int s0 = blockIdx.x * TQ;
  const int tid = threadIdx.x;
  const int lane = tid & 63, wid = tid >> 6;
  const int wm = wid >> 1, wn = wid & 1;
  const int quad = lane >> 4, l16 = lane & 15;

  __shared__ __align__(16) union {
    struct { f16 k[TK*BK]; f16 q[TQ*BK]; } s;   // 16KB + 16KB
    f16 P[TQ*TK];                               // 32KB, aliases k+q
  } u;
  __shared__ __align__(16) float red_l[2][TQ];  // 1KB

  // P swizzle: 16B chunk (col>>3) xor'd with row&7 (row stride 128 f16 = 256B)
#define P_IDX(row, col) ((size_t)(((row)<<7) | (((((col)>>3) ^ ((row)&7)))<<3) | ((col)&7)))

  float l_lane[16];
#pragma unroll
  for (int t=0;t<16;t++) l_lane[t] = 0.0f;

  float4_ o_acc[4][2];
#pragma unroll
  for (int i=0;i<4;i++)
#pragma unroll
    for (int j=0;j<2;j++) o_acc[i][j] = (float4_)0.0f;

  const f16* qbase = q16 + (size_t)(b*S_ + s0)*D_;
  const f16* kbase = k16 + (size_t)b*S_*D_;
  const f16* mrow  = mix16 + h*D_;
  const f16* vTb   = vT + (size_t)(b*D_ + h*HD_)*S_;

  // stage one 128x64 tile (1024 16B chunks, 4/thread), xor-swizzled chunk cols
#define STAGE_TILE(dstbase, srcbase) do {                                    \
    _Pragma("unroll")                                                        \
    for (int c_=0; c_<4; c_++) {                                             \
      int slot_ = (wid*4+c_)*64 + lane;                                      \
      int r_ = slot_ >> 3;                                                   \
      int gc_ = (slot_ & 7) ^ (r_ & 7);                                      \
      gl_lds16((srcbase) + (size_t)r_*D_ + gc_*8,                            \
               (dstbase) + (size_t)(wid*4+c_)*64*8);                         \
    } } while (0)

#pragma unroll 1
  for (int kt = 0; kt < S_; kt += TK) {
    float4_ sacc[4][4];
#pragma unroll
    for (int i=0;i<4;i++)
#pragma unroll
      for (int j=0;j<4;j++) sacc[i][j] = (float4_)0.0f;

    // ---- S = (q*mix) @ k^T over K=1024 ----
#pragma unroll 1
    for (int ko = 0; ko < D_; ko += BK) {
      STAGE_TILE(u.s.k, kbase + (size_t)kt*D_ + ko);
      STAGE_TILE(u.s.q, qbase + ko);
      __syncthreads();

      __builtin_amdgcn_s_setprio(1);
#pragma unroll
      for (int kk2=0; kk2<2; kk2++) {
        int ck = kk2*4 + quad;
        half8 mv = *(const half8*)&mrow[ko + kk2*32 + quad*8];
        half8 a[4], bf[4];
#pragma unroll
        for (int i=0;i<4;i++) {
          int rr = wm*64 + i*16 + l16;
          a[i] = *(const half8*)&u.s.q[(size_t)(((rr<<3) | (ck ^ (rr&7))) << 3)] * mv;
        }
#pragma unroll
        for (int j=0;j<4;j++) {
          int rr = wn*64 + j*16 + l16;
          bf[j] = *(const half8*)&u.s.k[(size_t)(((rr<<3) | (ck ^ (rr&7))) << 3)];
        }
#pragma unroll
        for (int i=0;i<4;i++)
#pragma unroll
          for (int j=0;j<4;j++)
            sacc[i][j] = __builtin_amdgcn_mfma_f32_16x16x32_f16(a[i], bf[j], sacc[i][j], 0,0,0);
      }
      __builtin_amdgcn_s_setprio(0);
      __syncthreads();   // k/q reads retired (last iter: frees region for P)
    }

    // ---- P = exp2(S), l partials, P->LDS (aliases k+q), PV ----
#pragma unroll
    for (int i=0;i<4;i++)
#pragma unroll
      for (int j=0;j<4;j++)
#pragma unroll
        for (int r=0;r<4;r++) {
          float p = __builtin_exp2f(sacc[i][j][r]);
          l_lane[i*4+r] += p;
          u.P[P_IDX(wm*64+i*16+quad*4+r, wn*64+j*16+l16)] = (f16)p;
        }

    // vb issued before the barrier: latency hides under it (transient regs)
    half8 vb[8];
#pragma unroll
    for (int ki=0; ki<4; ki++)
#pragma unroll
      for (int j=0; j<2; j++) {
        int ch = wn*32 + j*16 + l16;
        vb[ki*2+j] = *(const half8*)&vTb[(size_t)ch*S_ + kt + ki*32 + quad*8];
      }
    __syncthreads();

    __builtin_amdgcn_s_setprio(1);
#pragma unroll
    for (int ki=0; ki<4; ki++) {
      half8 pa[4];
#pragma unroll
      for (int i=0;i<4;i++)
        pa[i] = *(const half8*)&u.P[P_IDX(wm*64+i*16+l16, ki*32+quad*8)];
#pragma unroll
      for (int i=0;i<4;i++)
#pragma unroll
        for (int j=0;j<2;j++)
          o_acc[i][j] = __builtin_amdgcn_mfma_f32_16x16x32_f16(pa[i], vb[ki*2+j], o_acc[i][j], 0,0,0);
    }
    __builtin_amdgcn_s_setprio(0);
    __syncthreads();     // P reads retired -> next kt may stage over P
  }

  // ---- epilogue: single l reduction (butterfly over l16, cross-wave via LDS) ----
#pragma unroll
  for (int d=1; d<16; d<<=1)
#pragma unroll
    for (int t=0;t<16;t++) l_lane[t] += __shfl_xor(l_lane[t], d);
  if (l16 == 0) {
#pragma unroll
    for (int i=0;i<4;i++)
#pragma unroll
      for (int r=0;r<4;r++)
        red_l[wn][wm*64+i*16+quad*4+r] = l_lane[i*4+r];
  }
  __syncthreads();

#pragma unroll
  for (int i=0;i<4;i++) {
#pragma unroll
    for (int r=0;r<4;r++) {
      int row = wm*64 + i*16 + quad*4 + r;
      float linv = 1.0f / (red_l[0][row] + red_l[1][row]);
#pragma unroll
      for (int j=0;j<2;j++) {
        int colg = h*HD_ + wn*32 + j*16 + l16;
        out[(size_t)(b*S_ + s0 + row)*D_ + colg] = o_acc[i][j][r] * linv;
      }
    }
  }
}

// ---------------- launch ----------------
extern "C" void kernel_launch(void* const* d_in, const int* in_sizes, int n_in,
                              void* d_out, int out_size, void* d_ws, size_t ws_size,
                              hipStream_t stream) {
  (void)in_sizes; (void)n_in; (void)out_size; (void)ws_size;
  const float* hs  = (const float*)d_in[0];
  const float* Wq  = (const float*)d_in[1];
  const float* Wk  = (const float*)d_in[2];
  const float* Wv  = (const float*)d_in[3];
  const float* bv  = (const float*)d_in[4];
  const float* mix = (const float*)d_in[5];
  float* out = (float*)d_out;

  char* ws = (char*)d_ws;
  f16* hs16  = (f16*)(ws);                       // 8 MB
  f16* w16   = (f16*)(ws + 8388608);             // 6 MB
  f16* mix16 = (f16*)(ws + 14680064);            // 32 KB
  f16* q16   = (f16*)(ws + 14712832);            // 8 MB
  f16* k16   = (f16*)(ws + 23101440);            // 8 MB
  f16* vT    = (f16*)(ws + 31490048);            // 8 MB

  convert_kernel<<<2048, 256, 0, stream>>>(hs, Wq, Wk, Wv, mix,
                                           hs16, w16, w16+N_W, w16+2*N_W, mix16);
  qkv_kernel<<<dim3(D_/BN, (B_*S_)/BM, 3), 256, 0, stream>>>(
      hs16, w16, bv, q16, k16, vT);
  attn_kernel<<<dim3(S_/TQ, H_, B_), 256, 0, stream>>>(
      q16, k16, vT, mix16, out);
}